// Round 16
// baseline (544.337 us; speedup 1.0000x reference)
//
#include <hip/hip_runtime.h>
#include <hip/hip_bf16.h>
#include <math.h>

#define NN 100000
#define NE 1600000
#define NR 8
#define DD 64
#define DDR 64

typedef __attribute__((ext_vector_type(8))) short bf8v;   // 8 x bf16 (4 VGPRs)
typedef __attribute__((ext_vector_type(4))) float f4v;    // MFMA accumulator

// ---- helpers ----
__device__ __forceinline__ unsigned enc_f(float f) {
    unsigned u = __float_as_uint(f);
    return (u & 0x80000000u) ? ~u : (u | 0x80000000u);
}
__device__ __forceinline__ float dec_f(unsigned u) {
    return (u & 0x80000000u) ? __uint_as_float(u & 0x7FFFFFFFu) : __uint_as_float(~u);
}
__device__ __forceinline__ float bfs2f(unsigned short u) { return __uint_as_float(((unsigned)u) << 16); }
__device__ __forceinline__ short f2bfs(float x) {
    __hip_bfloat16 h = __float2bfloat16(x);
    return *reinterpret_cast<short*>(&h);
}
__device__ __forceinline__ unsigned pack2bf(short a, short b) {
    return (unsigned)(unsigned short)a | ((unsigned)(unsigned short)b << 16);
}
__device__ __forceinline__ float tanh_fast(float x) {
    x = fminf(fmaxf(x, -15.f), 15.f);
    float e = __expf(2.f * x);
    return (e - 1.f) * __builtin_amdgcn_rcpf(e + 1.f);
}

// ---- Kernel PM: tproj[r][n][c] = tanh(emb[n]@W_R[r] + rel[r]) via MFMA.
// Also emits bf16 emb sidecar (embh). proj itself is NO LONGER stored:
// attention is computed from w2 = W_R @ tproj (see k_projw2), so the only
// per-edge random gather left is embh (12.8 MB, cache-resident).
__global__ void __launch_bounds__(256)
k_projm(const float* __restrict__ emb, const float* __restrict__ WR,
        const float* __restrict__ rel,
        unsigned short* __restrict__ tproj, unsigned* __restrict__ embh)
{
    int t = threadIdx.x;
    int wv = t >> 6, l = t & 63;
    int lo = l & 15, hi = l >> 4;
    int r = blockIdx.y;
    int colbase = (wv & 1) * 32;
    int nwbase = blockIdx.x * 128 + (wv >> 1) * 64;

    const float* __restrict__ wb = WR + (long)r * (DD * DDR) + (hi * 8) * DDR + colbase + lo;
    bf8v B00, B01, B10, B11;
#pragma unroll
    for (int j = 0; j < 8; ++j) {
        B00[j] = f2bfs(wb[(0 * 32 + j) * DDR + 0]);
        B01[j] = f2bfs(wb[(1 * 32 + j) * DDR + 0]);
        B10[j] = f2bfs(wb[(0 * 32 + j) * DDR + 16]);
        B11[j] = f2bfs(wb[(1 * 32 + j) * DDR + 16]);
    }
    float rv0 = rel[r * DDR + colbase + lo];
    float rv1 = rel[r * DDR + colbase + lo + 16];

    for (int nt = 0; nt < 4; ++nt) {
        int nb = nwbase + nt * 16;
        int arow = nb + lo;
        float4 xa0 = make_float4(0.f, 0.f, 0.f, 0.f), xa1 = xa0, xb0 = xa0, xb1 = xa0;
        if (arow < NN) {
            const float* __restrict__ xr = emb + (long)arow * DD + hi * 8;
            xa0 = *(const float4*)(xr);
            xa1 = *(const float4*)(xr + 4);
            xb0 = *(const float4*)(xr + 32);
            xb1 = *(const float4*)(xr + 36);
        }
        bf8v A0, A1;
        A0[0] = f2bfs(xa0.x); A0[1] = f2bfs(xa0.y); A0[2] = f2bfs(xa0.z); A0[3] = f2bfs(xa0.w);
        A0[4] = f2bfs(xa1.x); A0[5] = f2bfs(xa1.y); A0[6] = f2bfs(xa1.z); A0[7] = f2bfs(xa1.w);
        A1[0] = f2bfs(xb0.x); A1[1] = f2bfs(xb0.y); A1[2] = f2bfs(xb0.z); A1[3] = f2bfs(xb0.w);
        A1[4] = f2bfs(xb1.x); A1[5] = f2bfs(xb1.y); A1[6] = f2bfs(xb1.z); A1[7] = f2bfs(xb1.w);

        if (r == 0 && arow < NN) {
            unsigned* er = embh + (long)arow * 32 + hi * 4;
            er[0]  = pack2bf(A0[0], A0[1]); er[1]  = pack2bf(A0[2], A0[3]);
            er[2]  = pack2bf(A0[4], A0[5]); er[3]  = pack2bf(A0[6], A0[7]);
            er[16] = pack2bf(A1[0], A1[1]); er[17] = pack2bf(A1[2], A1[3]);
            er[18] = pack2bf(A1[4], A1[5]); er[19] = pack2bf(A1[6], A1[7]);
        }

        f4v acc0 = {0.f, 0.f, 0.f, 0.f}, acc1 = {0.f, 0.f, 0.f, 0.f};
        acc0 = __builtin_amdgcn_mfma_f32_16x16x32_bf16(A0, B00, acc0, 0, 0, 0);
        acc0 = __builtin_amdgcn_mfma_f32_16x16x32_bf16(A1, B01, acc0, 0, 0, 0);
        acc1 = __builtin_amdgcn_mfma_f32_16x16x32_bf16(A0, B10, acc1, 0, 0, 0);
        acc1 = __builtin_amdgcn_mfma_f32_16x16x32_bf16(A1, B11, acc1, 0, 0, 0);

#pragma unroll
        for (int i = 0; i < 4; ++i) {
            int rr = nb + hi * 4 + i;
            if (rr < NN) {
                long obase = ((long)r * NN + rr) * DDR + colbase + lo;
                tproj[obase]      = (unsigned short)f2bfs(tanh_fast(acc0[i] + rv0));
                tproj[obase + 16] = (unsigned short)f2bfs(tanh_fast(acc1[i] + rv1));
            }
        }
    }
}

// ---- Kernel PW2: w2h[r][n][dd] = Σ_k tproj[r][n][k] * W_R[r][dd][k] ----
// (= tproj @ W_R^T per relation). att[e] then = Σ_dd embh[src,dd]*w2h[r,dst,dd].
__global__ void __launch_bounds__(256)
k_projw2(const unsigned short* __restrict__ tproj, const float* __restrict__ WR,
         unsigned short* __restrict__ w2h)
{
    int t = threadIdx.x;
    int wv = t >> 6, l = t & 63;
    int lo = l & 15, hi = l >> 4;
    int r = blockIdx.y;
    int colbase = (wv & 1) * 32;
    int nwbase = blockIdx.x * 128 + (wv >> 1) * 64;

    // B[k][col] = W_R[r][col][k]; lane: col=colbase+lo (+16 for acc1), k=hi*8+j
    const float* __restrict__ wb0 = WR + (long)r * (DD * DDR) + (long)(colbase + lo) * DDR + hi * 8;
    const float* __restrict__ wb1 = wb0 + 16 * DDR;
    bf8v B00, B01, B10, B11;
#pragma unroll
    for (int j = 0; j < 8; ++j) {
        B00[j] = f2bfs(wb0[j]);
        B01[j] = f2bfs(wb0[32 + j]);
        B10[j] = f2bfs(wb1[j]);
        B11[j] = f2bfs(wb1[32 + j]);
    }

    for (int nt = 0; nt < 4; ++nt) {
        int nb = nwbase + nt * 16;
        int arow = nb + lo;
        bf8v A0, A1;
#pragma unroll
        for (int j = 0; j < 8; ++j) { A0[j] = 0; A1[j] = 0; }
        if (arow < NN) {
            const unsigned short* ar = tproj + ((long)r * NN + arow) * DDR + hi * 8;
            A0 = *(const bf8v*)(ar);
            A1 = *(const bf8v*)(ar + 32);
        }
        f4v acc0 = {0.f, 0.f, 0.f, 0.f}, acc1 = {0.f, 0.f, 0.f, 0.f};
        acc0 = __builtin_amdgcn_mfma_f32_16x16x32_bf16(A0, B00, acc0, 0, 0, 0);
        acc0 = __builtin_amdgcn_mfma_f32_16x16x32_bf16(A1, B01, acc0, 0, 0, 0);
        acc1 = __builtin_amdgcn_mfma_f32_16x16x32_bf16(A0, B10, acc1, 0, 0, 0);
        acc1 = __builtin_amdgcn_mfma_f32_16x16x32_bf16(A1, B11, acc1, 0, 0, 0);
#pragma unroll
        for (int i = 0; i < 4; ++i) {
            int rr = nb + hi * 4 + i;
            if (rr < NN) {
                long obase = ((long)r * NN + rr) * DDR + colbase + lo;
                w2h[obase]      = (unsigned short)f2bfs(acc0[i]);
                w2h[obase + 16] = (unsigned short)f2bfs(acc1[i]);
            }
        }
    }
}

// ---- CSR build ----
__global__ void k_hist(const int* __restrict__ dst, unsigned* __restrict__ cnt)
{
    int e = blockIdx.x * blockDim.x + threadIdx.x;
    if (e >= NE) return;
    atomicAdd(cnt + dst[e], 1u);
}

__global__ void k_base(const unsigned* __restrict__ cnt, unsigned* __restrict__ gcur,
                       unsigned* __restrict__ base, unsigned* __restrict__ curs)
{
    int i = blockIdx.x * blockDim.x + threadIdx.x;
    int lane = threadIdx.x & 63;
    unsigned v = (i < NN) ? cnt[i] : 0u;
    unsigned p = v;
#pragma unroll
    for (int off = 1; off < 64; off <<= 1) {
        unsigned q = __shfl_up(p, off);
        if (lane >= off) p += q;
    }
    unsigned tot = __shfl(p, 63);
    unsigned gb = 0;
    if (lane == 0) gb = atomicAdd(gcur, tot);
    gb = __shfl(gb, 0);
    if (i < NN) {
        unsigned b = gb + p - v;
        base[i] = b;
        curs[i] = b;
    }
}

__global__ void k_scatter2(const int* __restrict__ dst, const int* __restrict__ src,
                           const int* __restrict__ et, unsigned* __restrict__ curs,
                           unsigned* __restrict__ srcet)
{
    int e = blockIdx.x * blockDim.x + threadIdx.x;
    if (e >= NE) return;
    unsigned pos = atomicAdd(curs + dst[e], 1u);
    srcet[pos] = (unsigned)src[e] | ((unsigned)et[e] << 28);
}

// ---- MEGA0W: attention via w2 (one embh gather per edge serves BOTH the
// att dot and the aggregation), softmax (exact no-max form), layer-0 MLP.
__global__ void __launch_bounds__(256)
k_mega0w(const float* __restrict__ emb, const unsigned short* __restrict__ embh,
         const unsigned short* __restrict__ w2h,
         const unsigned* __restrict__ cnt, const unsigned* __restrict__ basep,
         const unsigned* __restrict__ srcet, float* __restrict__ acsr,
         unsigned short* __restrict__ h1h,
         const float* __restrict__ W1, const float* __restrict__ b1,
         const float* __restrict__ W2, const float* __restrict__ b2,
         float* __restrict__ out)
{
    __shared__ float W1T[64][33];
    __shared__ float W2T[64][33];
    __shared__ float sm1[4][64];
    __shared__ float sm2[4][64];
    int t = threadIdx.x;
#pragma unroll
    for (int i = 0; i < 8; ++i) {
        int idx = i * 256 + t;          // j=idx>>6, dd=idx&63
        W1T[idx & 63][idx >> 6] = W1[idx];
        W2T[idx & 63][idx >> 6] = W2[idx];
    }
    int wv = t >> 6, lane = t & 63;
    int g = blockIdx.x * 4 + wv;        // NN % 4 == 0
    int deg = (int)cnt[g];
    long b = basep[g];
    float Nh = 0.f;
    if (deg > 0 && deg <= 64) {
        // preload this node's w2 row for all 8 relations (coalesced 128B each)
        float w0 = bfs2f(w2h[((long)0 * NN + g) * DDR + lane]);
        float w1_ = bfs2f(w2h[((long)1 * NN + g) * DDR + lane]);
        float w2_ = bfs2f(w2h[((long)2 * NN + g) * DDR + lane]);
        float w3 = bfs2f(w2h[((long)3 * NN + g) * DDR + lane]);
        float w4 = bfs2f(w2h[((long)4 * NN + g) * DDR + lane]);
        float w5 = bfs2f(w2h[((long)5 * NN + g) * DDR + lane]);
        float w6 = bfs2f(w2h[((long)6 * NN + g) * DDR + lane]);
        float w7 = bfs2f(w2h[((long)7 * NN + g) * DDR + lane]);
        unsigned se = 0;
        if (lane < deg) se = srcet[b + lane];       // coalesced CSR read
        float acc = 0.f, s_ = 0.f, myexp = 0.f;
        for (int i = 0; i < deg; i += 2) {
            int i1 = (i + 1 < deg) ? i + 1 : i;     // safe shfl index
            unsigned se0 = __shfl(se, i);
            unsigned se1 = __shfl(se, i1);
            int s0 = (int)(se0 & 0x0FFFFFFFu), r0 = (int)(se0 >> 28);
            int s1 = (int)(se1 & 0x0FFFFFFFu), r1 = (int)(se1 >> 28);
            float v0 = bfs2f(embh[(long)s0 * DD + lane]);   // random but 12.8MB: L2-hot
            float v1 = bfs2f(embh[(long)s1 * DD + lane]);
            float wa = (r0 & 4) ? ((r0 & 2) ? ((r0 & 1) ? w7 : w6) : ((r0 & 1) ? w5 : w4))
                                : ((r0 & 2) ? ((r0 & 1) ? w3 : w2_) : ((r0 & 1) ? w1_ : w0));
            float wbx = (r1 & 4) ? ((r1 & 2) ? ((r1 & 1) ? w7 : w6) : ((r1 & 1) ? w5 : w4))
                                 : ((r1 & 2) ? ((r1 & 1) ? w3 : w2_) : ((r1 & 1) ? w1_ : w0));
            float p0 = v0 * wa;
            float p1 = v1 * wbx;
#pragma unroll
            for (int off = 32; off; off >>= 1) {    // two independent reduces
                p0 += __shfl_xor(p0, off);
                p1 += __shfl_xor(p1, off);
            }
            float ex0 = __expf(fminf(p0, 60.f));
            float ex1 = (i + 1 < deg) ? __expf(fminf(p1, 60.f)) : 0.f;
            if (lane == i) myexp = ex0;
            if (lane == i + 1 && i + 1 < deg) myexp = ex1;
            s_ += ex0 + ex1;
            acc = fmaf(v0, ex0, fmaf(v1, ex1, acc));
        }
        float inv = 1.f / s_;
        if (lane < deg) acsr[b + lane] = myexp * inv;
        Nh = acc * inv;
    } else if (deg > 64) {
        // slow path: per-edge w2 row load (L1-hot after first per r)
        float s_ = 0.f, acc = 0.f;
        for (int i = 0; i < deg; ++i) {
            unsigned sei = srcet[b + i];
            int s = (int)(sei & 0x0FFFFFFFu), r = (int)(sei >> 28);
            float v = bfs2f(embh[(long)s * DD + lane]);
            float wvl = bfs2f(w2h[((long)r * NN + g) * DDR + lane]);
            float p = v * wvl;
#pragma unroll
            for (int off = 32; off; off >>= 1) p += __shfl_xor(p, off);
            float ex = __expf(fminf(p, 60.f));
            s_ += ex;
            acc = fmaf(v, ex, acc);
            if (lane == 0) acsr[b + i] = ex;
        }
        float inv = 1.f / s_;
        for (int i = lane; i < deg; i += 64) acsr[b + i] *= inv;
        Nh = acc * inv;
    }
    float x = emb[(long)g * DD + lane];
    sm1[wv][lane] = x + Nh;
    sm2[wv][lane] = x * Nh;
    __syncthreads();
    int j = lane & 31;
    const float* __restrict__ WT = (lane < 32) ? &W1T[0][0] : &W2T[0][0];
    const float* __restrict__ sm = (lane < 32) ? &sm1[wv][0] : &sm2[wv][0];
    float accm = (lane < 32) ? b1[j] : b2[j];
#pragma unroll 8
    for (int dd = 0; dd < 64; ++dd)
        accm = fmaf(sm[dd], WT[dd * 33 + j], accm);
    accm = (accm >= 0.f) ? accm : 0.01f * accm;
    float other = __shfl_down(accm, 32);
    float h = accm + other;
    float ss = h * h;
#pragma unroll
    for (int off = 16; off; off >>= 1) ss += __shfl_xor(ss, off);
    float hn = h / fmaxf(sqrtf(ss), 1e-12f);
    out[(long)g * 112 + lane] = x;
    if (lane < 32) {
        out[(long)g * 112 + 64 + j] = hn;
        h1h[(long)g * 32 + j] = (unsigned short)f2bfs(hn);
    }
}

// ---- MEGA1: layer-1 agg (bf16 h1 sidecar gathers, 6.4MB L2-resident) + MLP ----
__global__ void __launch_bounds__(256)
k_mega1(const float* __restrict__ acsr, const unsigned* __restrict__ srcet,
        const unsigned* __restrict__ cnt, const unsigned* __restrict__ basep,
        const unsigned short* __restrict__ h1h,
        const float* __restrict__ W1, const float* __restrict__ b1,
        const float* __restrict__ W2, const float* __restrict__ b2,
        float* __restrict__ out)
{
    __shared__ float W1T[32][17];
    __shared__ float W2T[32][17];
    __shared__ float sm1[8][32];
    __shared__ float sm2[8][32];
    int t = threadIdx.x;
#pragma unroll
    for (int i = 0; i < 2; ++i) {
        int idx = i * 256 + t;
        W1T[idx & 31][idx >> 5] = W1[idx];
        W2T[idx & 31][idx >> 5] = W2[idx];
    }
    int grp = t >> 5, l5 = t & 31;
    int g = blockIdx.x * 8 + grp;       // NN % 8 == 0
    int deg = (int)cnt[g];
    float acc = 0.f;
    if (deg > 0) {
        long b = basep[g];
        unsigned se = 0; float a = 0.f;
        if (l5 < deg) { se = srcet[b + l5]; a = acsr[b + l5]; }
        int dmin = (deg < 32) ? deg : 32;
        int i = 0;
        for (; i + 1 < dmin; i += 2) {
            float a0 = __shfl(a, i, 32), a1 = __shfl(a, i + 1, 32);
            int s0 = (int)(__shfl(se, i, 32) & 0x0FFFFFFFu);
            int s1 = (int)(__shfl(se, i + 1, 32) & 0x0FFFFFFFu);
            float v0 = bfs2f(h1h[(long)s0 * 32 + l5]);
            float v1 = bfs2f(h1h[(long)s1 * 32 + l5]);
            acc = fmaf(v0, a0, acc);
            acc = fmaf(v1, a1, acc);
        }
        if (i < dmin) {
            float a0 = __shfl(a, i, 32);
            int s0 = (int)(__shfl(se, i, 32) & 0x0FFFFFFFu);
            acc = fmaf(bfs2f(h1h[(long)s0 * 32 + l5]), a0, acc);
        }
        for (int k = 32; k < deg; ++k) {
            float ak = acsr[b + k];
            int sk = (int)(srcet[b + k] & 0x0FFFFFFFu);
            acc = fmaf(bfs2f(h1h[(long)sk * 32 + l5]), ak, acc);
        }
    }
    float x = out[(long)g * 112 + 64 + l5];
    sm1[grp][l5] = x + acc;
    sm2[grp][l5] = x * acc;
    __syncthreads();
    int j = l5 & 15;
    const float* __restrict__ WT = (l5 < 16) ? &W1T[0][0] : &W2T[0][0];
    const float* __restrict__ sm = (l5 < 16) ? &sm1[grp][0] : &sm2[grp][0];
    float accm = (l5 < 16) ? b1[j] : b2[j];
#pragma unroll 8
    for (int dd = 0; dd < 32; ++dd)
        accm = fmaf(sm[dd], WT[dd * 17 + j], accm);
    accm = (accm >= 0.f) ? accm : 0.01f * accm;
    float other = __shfl_down(accm, 16, 32);
    float h = accm + other;
    float ss = h * h;
#pragma unroll
    for (int off = 8; off; off >>= 1) ss += __shfl_xor(ss, off);
    float hn = h / fmaxf(sqrtf(ss), 1e-12f);
    if (l5 < 16) out[(long)g * 112 + 96 + j] = hn;
}

// ================= fallback path (ws too small): atomic pipeline =================
__global__ void k_att(const float* __restrict__ emb, const float* __restrict__ rel,
                      const float* __restrict__ WR, const int* __restrict__ src,
                      const int* __restrict__ dst, const int* __restrict__ et,
                      float* __restrict__ att, unsigned* __restrict__ mkey)
{
    int e = (int)((blockIdx.x * blockDim.x + threadIdx.x) >> 6);
    int lane = threadIdx.x & 63;
    if (e >= NE) return;
    int s = src[e], d = dst[e], r = et[e];
    const float* __restrict__ es = emb + (long)s * DD;
    const float* __restrict__ eh = emb + (long)d * DD;
    const float* __restrict__ w  = WR + r * (DD * DDR) + lane;
    float at = 0.f, ah = 0.f;
#pragma unroll 8
    for (int dd = 0; dd < DD; ++dd) {
        float ws = w[dd * DDR];
        at = fmaf(es[dd], ws, at);
        ah = fmaf(eh[dd], ws, ah);
    }
    float term = at * tanhf(ah + rel[r * DDR + lane]);
#pragma unroll
    for (int off = 32; off; off >>= 1) term += __shfl_xor(term, off);
    if (lane == 0) {
        att[e] = term;
        atomicMax(mkey + d, enc_f(term));
    }
}

__global__ void k_expsum(const int* __restrict__ dst, float* __restrict__ att,
                         const unsigned* __restrict__ mkey, float* __restrict__ ssum)
{
    int e = blockIdx.x * blockDim.x + threadIdx.x;
    if (e >= NE) return;
    int d = dst[e];
    float ex = expf(att[e] - dec_f(mkey[d]));
    att[e] = ex;
    atomicAdd(ssum + d, ex);
}

__global__ void k_agg0(const float* __restrict__ emb, const int* __restrict__ src,
                       const int* __restrict__ dst, float* __restrict__ att,
                       const float* __restrict__ ssum, float* __restrict__ Nh)
{
    int e = (int)((blockIdx.x * blockDim.x + threadIdx.x) >> 6);
    int lane = threadIdx.x & 63;
    if (e >= NE) return;
    int s = src[e], d = dst[e];
    float a = att[e] / ssum[d];
    if (lane == 0) att[e] = a;
    float v = emb[(long)s * DD + lane] * a;
    atomicAdd(Nh + (long)d * DD + lane, v);
}

__global__ void k_agg1(const float* __restrict__ out, const int* __restrict__ src,
                       const int* __restrict__ dst, const float* __restrict__ att,
                       float* __restrict__ Nh1)
{
    int idx = blockIdx.x * blockDim.x + threadIdx.x;
    int e = idx >> 5;
    int j = idx & 31;
    if (e >= NE) return;
    int s = src[e], d = dst[e];
    float a = att[e];
    float v = out[(long)s * 112 + 64 + j] * a;
    atomicAdd(Nh1 + (long)d * 32 + j, v);
}

#define NPB0 32
__global__ void __launch_bounds__(256)
k_node0t(const float* __restrict__ emb, const float* __restrict__ Nh,
         const float* __restrict__ W1, const float* __restrict__ b1,
         const float* __restrict__ W2, const float* __restrict__ b2,
         float* __restrict__ out)
{
    __shared__ float W1T[64][33];
    __shared__ float W2T[64][33];
    int t = threadIdx.x;
#pragma unroll
    for (int i = 0; i < 8; ++i) {
        int idx = i * 256 + t;
        W1T[idx & 63][idx >> 6] = W1[idx];
        W2T[idx & 63][idx >> 6] = W2[idx];
    }
    __syncthreads();
    int wv = t >> 6, lane = t & 63, j = lane & 31;
    const float* __restrict__ WT = (lane < 32) ? &W1T[0][0] : &W2T[0][0];
    float bj = (lane < 32) ? b1[j] : b2[j];
    int n0 = blockIdx.x * NPB0;
    int n1 = (n0 + NPB0 < NN) ? n0 + NPB0 : NN;
    for (int node = n0 + wv; node < n1; node += 4) {
        const float* __restrict__ x  = emb + (long)node * DD;
        const float* __restrict__ nh = Nh + (long)node * DD;
        float acc = 0.f;
#pragma unroll 8
        for (int dd = 0; dd < DD; ++dd) {
            float xv = x[dd], nv = nh[dd];
            float v = (lane < 32) ? (xv + nv) : (xv * nv);
            acc = fmaf(v, WT[dd * 33 + j], acc);
        }
        acc += bj;
        acc = (acc >= 0.f) ? acc : 0.01f * acc;
        float other = __shfl_down(acc, 32);
        float h = acc + other;
        float ss = h * h;
#pragma unroll
        for (int off = 16; off; off >>= 1) ss += __shfl_xor(ss, off);
        float hn = h / fmaxf(sqrtf(ss), 1e-12f);
        out[(long)node * 112 + lane] = x[lane];
        if (lane < 32) out[(long)node * 112 + 64 + j] = hn;
    }
}

#define NPB1 32
__global__ void __launch_bounds__(256)
k_node1t(const float* __restrict__ outbuf, const float* __restrict__ Nh1,
         const float* __restrict__ W1, const float* __restrict__ b1,
         const float* __restrict__ W2, const float* __restrict__ b2,
         float* __restrict__ out)
{
    __shared__ float W1T[32][17];
    __shared__ float W2T[32][17];
    int t = threadIdx.x;
#pragma unroll
    for (int i = 0; i < 2; ++i) {
        int idx = i * 256 + t;
        W1T[idx & 31][idx >> 5] = W1[idx];
        W2T[idx & 31][idx >> 5] = W2[idx];
    }
    __syncthreads();
    int grp = t >> 5;
    int l5 = t & 31, j = l5 & 15;
    const float* __restrict__ WT = (l5 < 16) ? &W1T[0][0] : &W2T[0][0];
    float bj = (l5 < 16) ? b1[j] : b2[j];
    int n0 = blockIdx.x * NPB1;
    int n1 = (n0 + NPB1 < NN) ? n0 + NPB1 : NN;
    for (int node = n0 + grp; node < n1; node += 8) {
        const float* __restrict__ x  = outbuf + (long)node * 112 + 64;
        const float* __restrict__ nh = Nh1 + (long)node * 32;
        float acc = 0.f;
#pragma unroll 8
        for (int dd = 0; dd < 32; ++dd) {
            float xv = x[dd], nv = nh[dd];
            float v = (l5 < 16) ? (xv + nv) : (xv * nv);
            acc = fmaf(v, WT[dd * 17 + j], acc);
        }
        acc += bj;
        acc = (acc >= 0.f) ? acc : 0.01f * acc;
        float other = __shfl_down(acc, 16, 32);
        float h = acc + other;
        float ss = h * h;
#pragma unroll
        for (int off = 8; off; off >>= 1) ss += __shfl_xor(ss, off);
        float hn = h / fmaxf(sqrtf(ss), 1e-12f);
        if (l5 < 16) out[(long)node * 112 + 96 + j] = hn;
    }
}

extern "C" void kernel_launch(void* const* d_in, const int* in_sizes, int n_in,
                              void* d_out, int out_size, void* d_ws, size_t ws_size,
                              hipStream_t stream) {
    const float* emb  = (const float*)d_in[0];
    const float* rel  = (const float*)d_in[1];
    const float* WR   = (const float*)d_in[2];
    const float* W1_0 = (const float*)d_in[3];
    const float* b1_0 = (const float*)d_in[4];
    const float* W2_0 = (const float*)d_in[5];
    const float* b2_0 = (const float*)d_in[6];
    const float* W1_1 = (const float*)d_in[7];
    const float* b1_1 = (const float*)d_in[8];
    const float* W2_1 = (const float*)d_in[9];
    const float* b2_1 = (const float*)d_in[10];
    const int*   src  = (const int*)d_in[11];
    const int*   dst  = (const int*)d_in[12];
    const int*   et   = (const int*)d_in[13];
    float* out = (float*)d_out;

    // main-path workspace (4B units):
    // [cnt NN][gcur 64][base NN][curs NN][acsr NE][srcet NE][tproj][w2h][embh NN*32][h1h NN*16]
    unsigned* cnt   = (unsigned*)d_ws;
    unsigned* gcur  = cnt + NN;
    unsigned* basep = cnt + NN + 64;
    unsigned* curs  = cnt + 2 * NN + 64;
    float* acsr  = (float*)d_ws + 3 * NN + 64;
    unsigned* srcet = (unsigned*)(acsr + NE);
    unsigned short* tproj = (unsigned short*)(srcet + NE);
    unsigned short* w2h = tproj + (size_t)NR * NN * DDR;
    unsigned* embh = (unsigned*)(w2h + (size_t)NR * NN * DDR);
    unsigned short* h1h = (unsigned short*)(embh + (size_t)NN * 32);

    size_t need = ((size_t)3 * NN + 64 + 2 * (size_t)NE) * 4
                + 2 * (size_t)NR * NN * DDR * 2
                + (size_t)NN * 32 * 4 + (size_t)NN * 16 * 4;

    if (ws_size >= need) {
        hipMemsetAsync(d_ws, 0, (size_t)(NN + 64) * sizeof(unsigned), stream);  // cnt + gcur
        k_hist<<<dim3((NE + 255) / 256), dim3(256), 0, stream>>>(dst, cnt);
        k_projm<<<dim3((NN + 127) / 128, NR), dim3(256), 0, stream>>>(
            emb, WR, rel, tproj, embh);
        k_projw2<<<dim3((NN + 127) / 128, NR), dim3(256), 0, stream>>>(
            tproj, WR, w2h);
        k_base<<<dim3((NN + 255) / 256), dim3(256), 0, stream>>>(cnt, gcur, basep, curs);
        k_scatter2<<<dim3((NE + 255) / 256), dim3(256), 0, stream>>>(
            dst, src, et, curs, srcet);
        k_mega0w<<<dim3((NN + 3) / 4), dim3(256), 0, stream>>>(
            emb, (const unsigned short*)embh, w2h, cnt, basep, srcet, acsr, h1h,
            W1_0, b1_0, W2_0, b2_0, out);
        k_mega1<<<dim3((NN + 7) / 8), dim3(256), 0, stream>>>(
            acsr, srcet, cnt, basep, h1h, W1_1, b1_1, W2_1, b2_1, out);
    } else {
        // fallback: atomic pipeline
        unsigned* mkey = (unsigned*)d_ws;
        float* ssum = (float*)d_ws + NN;
        float* fNh0 = (float*)d_ws + 2 * NN;
        float* fNh1 = (float*)d_ws + (2 + DD) * NN;
        float* fatt = (float*)d_ws + (2 + DD + 32) * NN;
        hipMemsetAsync(d_ws, 0, (size_t)(2 + DD + 32) * NN * sizeof(float), stream);
        k_att<<<dim3((int)(((long)NE * 64 + 255) / 256)), dim3(256), 0, stream>>>(
            emb, rel, WR, src, dst, et, fatt, mkey);
        k_expsum<<<dim3((NE + 255) / 256), dim3(256), 0, stream>>>(dst, fatt, mkey, ssum);
        k_agg0<<<dim3((int)(((long)NE * 64 + 255) / 256)), dim3(256), 0, stream>>>(
            emb, src, dst, fatt, ssum, fNh0);
        k_node0t<<<dim3((NN + NPB0 - 1) / NPB0), dim3(256), 0, stream>>>(
            emb, fNh0, W1_0, b1_0, W2_0, b2_0, out);
        k_agg1<<<dim3((int)(((long)NE * 32 + 255) / 256)), dim3(256), 0, stream>>>(
            out, src, dst, fatt, fNh1);
        k_node1t<<<dim3((NN + NPB1 - 1) / NPB1), dim3(256), 0, stream>>>(
            out, fNh1, W1_1, b1_1, W2_1, b2_1, out);
    }
}

// Round 17
// 536.522 us; speedup vs baseline: 1.0146x; 1.0146x over previous
//
#include <hip/hip_runtime.h>
#include <hip/hip_bf16.h>
#include <math.h>

#define NN 100000
#define NE 1600000
#define NR 8
#define DD 64
#define DDR 64

typedef __attribute__((ext_vector_type(8))) short bf8v;   // 8 x bf16 (4 VGPRs)
typedef __attribute__((ext_vector_type(4))) float f4v;    // MFMA accumulator

// ---- helpers ----
__device__ __forceinline__ unsigned enc_f(float f) {
    unsigned u = __float_as_uint(f);
    return (u & 0x80000000u) ? ~u : (u | 0x80000000u);
}
__device__ __forceinline__ float dec_f(unsigned u) {
    return (u & 0x80000000u) ? __uint_as_float(u & 0x7FFFFFFFu) : __uint_as_float(~u);
}
__device__ __forceinline__ float bflo(unsigned u) { return __uint_as_float(u << 16); }
__device__ __forceinline__ float bfhi(unsigned u) { return __uint_as_float(u & 0xFFFF0000u); }
__device__ __forceinline__ float bfs2f(unsigned short u) { return __uint_as_float(((unsigned)u) << 16); }
__device__ __forceinline__ short f2bfs(float x) {
    __hip_bfloat16 h = __float2bfloat16(x);
    return *reinterpret_cast<short*>(&h);
}
__device__ __forceinline__ unsigned pack2bf(short a, short b) {
    return (unsigned)(unsigned short)a | ((unsigned)(unsigned short)b << 16);
}
__device__ __forceinline__ float tanh_fast(float x) {
    x = fminf(fmaxf(x, -15.f), 15.f);
    float e = __expf(2.f * x);
    return (e - 1.f) * __builtin_amdgcn_rcpf(e + 1.f);
}

// ---- Kernel PM: tproj[r][n][c] = tanh(emb[n]@W_R[r] + rel[r]) via MFMA;
// also emits bf16 emb sidecar embh (12.8MB, the ONLY per-edge random-gather
// target downstream -> L2-resident).
__global__ void __launch_bounds__(256)
k_projm(const float* __restrict__ emb, const float* __restrict__ WR,
        const float* __restrict__ rel,
        unsigned short* __restrict__ tproj, unsigned* __restrict__ embh)
{
    int t = threadIdx.x;
    int wv = t >> 6, l = t & 63;
    int lo = l & 15, hi = l >> 4;
    int r = blockIdx.y;
    int colbase = (wv & 1) * 32;
    int nwbase = blockIdx.x * 128 + (wv >> 1) * 64;

    const float* __restrict__ wb = WR + (long)r * (DD * DDR) + (hi * 8) * DDR + colbase + lo;
    bf8v B00, B01, B10, B11;
#pragma unroll
    for (int j = 0; j < 8; ++j) {
        B00[j] = f2bfs(wb[(0 * 32 + j) * DDR + 0]);
        B01[j] = f2bfs(wb[(1 * 32 + j) * DDR + 0]);
        B10[j] = f2bfs(wb[(0 * 32 + j) * DDR + 16]);
        B11[j] = f2bfs(wb[(1 * 32 + j) * DDR + 16]);
    }
    float rv0 = rel[r * DDR + colbase + lo];
    float rv1 = rel[r * DDR + colbase + lo + 16];

    for (int nt = 0; nt < 4; ++nt) {
        int nb = nwbase + nt * 16;
        int arow = nb + lo;
        float4 xa0 = make_float4(0.f, 0.f, 0.f, 0.f), xa1 = xa0, xb0 = xa0, xb1 = xa0;
        if (arow < NN) {
            const float* __restrict__ xr = emb + (long)arow * DD + hi * 8;
            xa0 = *(const float4*)(xr);
            xa1 = *(const float4*)(xr + 4);
            xb0 = *(const float4*)(xr + 32);
            xb1 = *(const float4*)(xr + 36);
        }
        bf8v A0, A1;
        A0[0] = f2bfs(xa0.x); A0[1] = f2bfs(xa0.y); A0[2] = f2bfs(xa0.z); A0[3] = f2bfs(xa0.w);
        A0[4] = f2bfs(xa1.x); A0[5] = f2bfs(xa1.y); A0[6] = f2bfs(xa1.z); A0[7] = f2bfs(xa1.w);
        A1[0] = f2bfs(xb0.x); A1[1] = f2bfs(xb0.y); A1[2] = f2bfs(xb0.z); A1[3] = f2bfs(xb0.w);
        A1[4] = f2bfs(xb1.x); A1[5] = f2bfs(xb1.y); A1[6] = f2bfs(xb1.z); A1[7] = f2bfs(xb1.w);

        if (r == 0 && arow < NN) {
            unsigned* er = embh + (long)arow * 32 + hi * 4;
            er[0]  = pack2bf(A0[0], A0[1]); er[1]  = pack2bf(A0[2], A0[3]);
            er[2]  = pack2bf(A0[4], A0[5]); er[3]  = pack2bf(A0[6], A0[7]);
            er[16] = pack2bf(A1[0], A1[1]); er[17] = pack2bf(A1[2], A1[3]);
            er[18] = pack2bf(A1[4], A1[5]); er[19] = pack2bf(A1[6], A1[7]);
        }

        f4v acc0 = {0.f, 0.f, 0.f, 0.f}, acc1 = {0.f, 0.f, 0.f, 0.f};
        acc0 = __builtin_amdgcn_mfma_f32_16x16x32_bf16(A0, B00, acc0, 0, 0, 0);
        acc0 = __builtin_amdgcn_mfma_f32_16x16x32_bf16(A1, B01, acc0, 0, 0, 0);
        acc1 = __builtin_amdgcn_mfma_f32_16x16x32_bf16(A0, B10, acc1, 0, 0, 0);
        acc1 = __builtin_amdgcn_mfma_f32_16x16x32_bf16(A1, B11, acc1, 0, 0, 0);

#pragma unroll
        for (int i = 0; i < 4; ++i) {
            int rr = nb + hi * 4 + i;
            if (rr < NN) {
                long obase = ((long)r * NN + rr) * DDR + colbase + lo;
                tproj[obase]      = (unsigned short)f2bfs(tanh_fast(acc0[i] + rv0));
                tproj[obase + 16] = (unsigned short)f2bfs(tanh_fast(acc1[i] + rv1));
            }
        }
    }
}

// ---- Kernel PW2: w2h[r][n][dd] = Σ_k tproj[r][n][k] * W_R[r][dd][k] ----
__global__ void __launch_bounds__(256)
k_projw2(const unsigned short* __restrict__ tproj, const float* __restrict__ WR,
         unsigned short* __restrict__ w2h)
{
    int t = threadIdx.x;
    int wv = t >> 6, l = t & 63;
    int lo = l & 15, hi = l >> 4;
    int r = blockIdx.y;
    int colbase = (wv & 1) * 32;
    int nwbase = blockIdx.x * 128 + (wv >> 1) * 64;

    const float* __restrict__ wb0 = WR + (long)r * (DD * DDR) + (long)(colbase + lo) * DDR + hi * 8;
    const float* __restrict__ wb1 = wb0 + 16 * DDR;
    bf8v B00, B01, B10, B11;
#pragma unroll
    for (int j = 0; j < 8; ++j) {
        B00[j] = f2bfs(wb0[j]);
        B01[j] = f2bfs(wb0[32 + j]);
        B10[j] = f2bfs(wb1[j]);
        B11[j] = f2bfs(wb1[32 + j]);
    }

    for (int nt = 0; nt < 4; ++nt) {
        int nb = nwbase + nt * 16;
        int arow = nb + lo;
        bf8v A0, A1;
#pragma unroll
        for (int j = 0; j < 8; ++j) { A0[j] = 0; A1[j] = 0; }
        if (arow < NN) {
            const unsigned short* ar = tproj + ((long)r * NN + arow) * DDR + hi * 8;
            A0 = *(const bf8v*)(ar);
            A1 = *(const bf8v*)(ar + 32);
        }
        f4v acc0 = {0.f, 0.f, 0.f, 0.f}, acc1 = {0.f, 0.f, 0.f, 0.f};
        acc0 = __builtin_amdgcn_mfma_f32_16x16x32_bf16(A0, B00, acc0, 0, 0, 0);
        acc0 = __builtin_amdgcn_mfma_f32_16x16x32_bf16(A1, B01, acc0, 0, 0, 0);
        acc1 = __builtin_amdgcn_mfma_f32_16x16x32_bf16(A0, B10, acc1, 0, 0, 0);
        acc1 = __builtin_amdgcn_mfma_f32_16x16x32_bf16(A1, B11, acc1, 0, 0, 0);
#pragma unroll
        for (int i = 0; i < 4; ++i) {
            int rr = nb + hi * 4 + i;
            if (rr < NN) {
                long obase = ((long)r * NN + rr) * DDR + colbase + lo;
                w2h[obase]      = (unsigned short)f2bfs(acc0[i]);
                w2h[obase + 16] = (unsigned short)f2bfs(acc1[i]);
            }
        }
    }
}

// ---- CSR build ----
__global__ void k_hist(const int* __restrict__ dst, unsigned* __restrict__ cnt)
{
    int e = blockIdx.x * blockDim.x + threadIdx.x;
    if (e >= NE) return;
    atomicAdd(cnt + dst[e], 1u);
}

__global__ void k_base(const unsigned* __restrict__ cnt, unsigned* __restrict__ gcur,
                       unsigned* __restrict__ base, unsigned* __restrict__ curs)
{
    int i = blockIdx.x * blockDim.x + threadIdx.x;
    int lane = threadIdx.x & 63;
    unsigned v = (i < NN) ? cnt[i] : 0u;
    unsigned p = v;
#pragma unroll
    for (int off = 1; off < 64; off <<= 1) {
        unsigned q = __shfl_up(p, off);
        if (lane >= off) p += q;
    }
    unsigned tot = __shfl(p, 63);
    unsigned gb = 0;
    if (lane == 0) gb = atomicAdd(gcur, tot);
    gb = __shfl(gb, 0);
    if (i < NN) {
        unsigned b = gb + p - v;
        base[i] = b;
        curs[i] = b;
    }
}

__global__ void k_scatter2(const int* __restrict__ dst, const int* __restrict__ src,
                           const int* __restrict__ et, unsigned* __restrict__ curs,
                           unsigned* __restrict__ srcet)
{
    int e = blockIdx.x * blockDim.x + threadIdx.x;
    if (e >= NE) return;
    unsigned pos = atomicAdd(curs + dst[e], 1u);
    srcet[pos] = (unsigned)src[e] | ((unsigned)et[e] << 28);
}

// ---- MEGA0: r13's 16-lane x 4-edge attention structure, r16's operands.
// att dot: embh[src] (L2-resident 12.8MB) . w2h[r,dst] (L1-hot). No tanh,
// no rel, no select tree. agg gathers bf16 embh. Max-subtracted softmax
// via att_s LDS staging (r13-verified).
__global__ void __launch_bounds__(256)
k_mega0(const float* __restrict__ emb, const unsigned* __restrict__ embh,
        const unsigned* __restrict__ w2h,
        const unsigned* __restrict__ cnt, const unsigned* __restrict__ basep,
        const unsigned* __restrict__ srcet, float* __restrict__ acsr,
        unsigned short* __restrict__ h1h,
        const float* __restrict__ W1, const float* __restrict__ b1,
        const float* __restrict__ W2, const float* __restrict__ b2,
        float* __restrict__ out)
{
    __shared__ float W1T[64][33];
    __shared__ float W2T[64][33];
    __shared__ float sm1[4][64];
    __shared__ float sm2[4][64];
    __shared__ float att_s[4][64];
    int t = threadIdx.x;
#pragma unroll
    for (int i = 0; i < 8; ++i) {
        int idx = i * 256 + t;          // j=idx>>6, dd=idx&63
        W1T[idx & 63][idx >> 6] = W1[idx];
        W2T[idx & 63][idx >> 6] = W2[idx];
    }
    int wv = t >> 6, lane = t & 63;
    int g = blockIdx.x * 4 + wv;        // NN % 4 == 0
    int deg = (int)cnt[g];
    long b = basep[g];
    float Nh = 0.f;
    const unsigned short* embh_us = (const unsigned short*)embh;
    if (deg > 0 && deg <= 64) {
        unsigned se = 0;
        if (lane < deg) se = srcet[b + lane];       // coalesced CSR read
        int gi = lane >> 4;             // edge sub-slot 0..3
        int lj = lane & 15;             // lane within edge group
        for (int k0 = 0; k0 < deg; k0 += 4) {
            int ei = k0 + gi;
            unsigned sei = __shfl(se, ei);          // pad-safe (se=0)
            int s = (int)(sei & 0x0FFFFFFFu);
            int r = (int)(sei >> 28);
            uint2 tv = *(const uint2*)(embh + (long)s * 32 + lj * 2);          // L2-hot
            uint2 hv = *(const uint2*)(w2h + ((long)r * NN + g) * 32 + lj * 2); // L1-hot
            float sum = bflo(tv.x) * bflo(hv.x) + bfhi(tv.x) * bfhi(hv.x)
                      + bflo(tv.y) * bflo(hv.y) + bfhi(tv.y) * bfhi(hv.y);
#pragma unroll
            for (int off = 8; off; off >>= 1) sum += __shfl_xor(sum, off);
            if (lj == 0 && ei < deg) att_s[wv][ei] = sum;
        }
        float attv = (lane < deg) ? att_s[wv][lane] : -3.4e38f;
        float m = attv;
#pragma unroll
        for (int off = 32; off; off >>= 1) m = fmaxf(m, __shfl_xor(m, off));
        float exv = (lane < deg) ? __expf(attv - m) : 0.f;
        float s_ = exv;
#pragma unroll
        for (int off = 32; off; off >>= 1) s_ += __shfl_xor(s_, off);
        float inv = 1.f / s_;
        if (lane < deg) acsr[b + lane] = exv * inv;
        // agg: bf16 embh gathers (128B rows, L2-resident), 2-way unroll
        float acc = 0.f;
        int i = 0;
        for (; i + 1 < deg; i += 2) {
            float a0 = __shfl(exv, i), a1 = __shfl(exv, i + 1);
            int s0 = (int)(__shfl(se, i) & 0x0FFFFFFFu);
            int s1 = (int)(__shfl(se, i + 1) & 0x0FFFFFFFu);
            float v0 = bfs2f(embh_us[(long)s0 * DD + lane]);
            float v1 = bfs2f(embh_us[(long)s1 * DD + lane]);
            acc = fmaf(v0, a0, acc);
            acc = fmaf(v1, a1, acc);
        }
        if (i < deg) {
            float a0 = __shfl(exv, i);
            int s0 = (int)(__shfl(se, i) & 0x0FFFFFFFu);
            acc = fmaf(bfs2f(embh_us[(long)s0 * DD + lane]), a0, acc);
        }
        Nh = acc * inv;
    } else if (deg > 64) {
        // slow path (deg>64), full-lane, correctness-first
        float m = -3.4e38f;
        for (int i = 0; i < deg; ++i) {
            unsigned sei = srcet[b + i];
            int s = (int)(sei & 0x0FFFFFFFu), r = (int)(sei >> 28);
            float v = bfs2f(embh_us[(long)s * DD + lane]);
            float wvl = bfs2f(((const unsigned short*)w2h)[((long)r * NN + g) * DDR + lane]);
            float p = v * wvl;
#pragma unroll
            for (int off = 32; off; off >>= 1) p += __shfl_xor(p, off);
            if (lane == 0) acsr[b + i] = p;
            m = fmaxf(m, p);
        }
        float s_ = 0.f;
        for (int i = lane; i < deg; i += 64) s_ += __expf(acsr[b + i] - m);
#pragma unroll
        for (int off = 32; off; off >>= 1) s_ += __shfl_xor(s_, off);
        float inv = 1.f / s_;
        float acc = 0.f;
        for (int i = 0; i < deg; ++i) {
            float raw = acsr[b + i];
            float a = __expf(raw - m) * inv;
            int s = (int)(srcet[b + i] & 0x0FFFFFFFu);
            acc = fmaf(bfs2f(embh_us[(long)s * DD + lane]), a, acc);
            if (lane == 0) acsr[b + i] = a;
        }
        Nh = acc;
    }
    float x = emb[(long)g * DD + lane];
    sm1[wv][lane] = x + Nh;
    sm2[wv][lane] = x * Nh;
    __syncthreads();
    int j = lane & 31;
    const float* __restrict__ WT = (lane < 32) ? &W1T[0][0] : &W2T[0][0];
    const float* __restrict__ sm = (lane < 32) ? &sm1[wv][0] : &sm2[wv][0];
    float accm = (lane < 32) ? b1[j] : b2[j];
#pragma unroll 8
    for (int dd = 0; dd < 64; ++dd)
        accm = fmaf(sm[dd], WT[dd * 33 + j], accm);
    accm = (accm >= 0.f) ? accm : 0.01f * accm;
    float other = __shfl_down(accm, 32);
    float h = accm + other;
    float ss = h * h;
#pragma unroll
    for (int off = 16; off; off >>= 1) ss += __shfl_xor(ss, off);
    float hn = h / fmaxf(sqrtf(ss), 1e-12f);
    out[(long)g * 112 + lane] = x;
    if (lane < 32) {
        out[(long)g * 112 + 64 + j] = hn;
        h1h[(long)g * 32 + j] = (unsigned short)f2bfs(hn);
    }
}

// ---- MEGA1: layer-1 agg (bf16 h1h gathers, 6.4MB L2-resident) + MLP ----
__global__ void __launch_bounds__(256)
k_mega1(const float* __restrict__ acsr, const unsigned* __restrict__ srcet,
        const unsigned* __restrict__ cnt, const unsigned* __restrict__ basep,
        const unsigned short* __restrict__ h1h,
        const float* __restrict__ W1, const float* __restrict__ b1,
        const float* __restrict__ W2, const float* __restrict__ b2,
        float* __restrict__ out)
{
    __shared__ float W1T[32][17];
    __shared__ float W2T[32][17];
    __shared__ float sm1[8][32];
    __shared__ float sm2[8][32];
    int t = threadIdx.x;
#pragma unroll
    for (int i = 0; i < 2; ++i) {
        int idx = i * 256 + t;
        W1T[idx & 31][idx >> 5] = W1[idx];
        W2T[idx & 31][idx >> 5] = W2[idx];
    }
    int grp = t >> 5, l5 = t & 31;
    int g = blockIdx.x * 8 + grp;       // NN % 8 == 0
    int deg = (int)cnt[g];
    float acc = 0.f;
    if (deg > 0) {
        long b = basep[g];
        unsigned se = 0; float a = 0.f;
        if (l5 < deg) { se = srcet[b + l5]; a = acsr[b + l5]; }
        int dmin = (deg < 32) ? deg : 32;
        int i = 0;
        for (; i + 1 < dmin; i += 2) {
            float a0 = __shfl(a, i, 32), a1 = __shfl(a, i + 1, 32);
            int s0 = (int)(__shfl(se, i, 32) & 0x0FFFFFFFu);
            int s1 = (int)(__shfl(se, i + 1, 32) & 0x0FFFFFFFu);
            float v0 = bfs2f(h1h[(long)s0 * 32 + l5]);
            float v1 = bfs2f(h1h[(long)s1 * 32 + l5]);
            acc = fmaf(v0, a0, acc);
            acc = fmaf(v1, a1, acc);
        }
        if (i < dmin) {
            float a0 = __shfl(a, i, 32);
            int s0 = (int)(__shfl(se, i, 32) & 0x0FFFFFFFu);
            acc = fmaf(bfs2f(h1h[(long)s0 * 32 + l5]), a0, acc);
        }
        for (int k = 32; k < deg; ++k) {
            float ak = acsr[b + k];
            int sk = (int)(srcet[b + k] & 0x0FFFFFFFu);
            acc = fmaf(bfs2f(h1h[(long)sk * 32 + l5]), ak, acc);
        }
    }
    float x = out[(long)g * 112 + 64 + l5];
    sm1[grp][l5] = x + acc;
    sm2[grp][l5] = x * acc;
    __syncthreads();
    int j = l5 & 15;
    const float* __restrict__ WT = (l5 < 16) ? &W1T[0][0] : &W2T[0][0];
    const float* __restrict__ sm = (l5 < 16) ? &sm1[grp][0] : &sm2[grp][0];
    float accm = (l5 < 16) ? b1[j] : b2[j];
#pragma unroll 8
    for (int dd = 0; dd < 32; ++dd)
        accm = fmaf(sm[dd], WT[dd * 17 + j], accm);
    accm = (accm >= 0.f) ? accm : 0.01f * accm;
    float other = __shfl_down(accm, 16, 32);
    float h = accm + other;
    float ss = h * h;
#pragma unroll
    for (int off = 8; off; off >>= 1) ss += __shfl_xor(ss, off);
    float hn = h / fmaxf(sqrtf(ss), 1e-12f);
    if (l5 < 16) out[(long)g * 112 + 96 + j] = hn;
}

// ================= fallback path (ws too small): atomic pipeline =================
__global__ void k_att(const float* __restrict__ emb, const float* __restrict__ rel,
                      const float* __restrict__ WR, const int* __restrict__ src,
                      const int* __restrict__ dst, const int* __restrict__ et,
                      float* __restrict__ att, unsigned* __restrict__ mkey)
{
    int e = (int)((blockIdx.x * blockDim.x + threadIdx.x) >> 6);
    int lane = threadIdx.x & 63;
    if (e >= NE) return;
    int s = src[e], d = dst[e], r = et[e];
    const float* __restrict__ es = emb + (long)s * DD;
    const float* __restrict__ eh = emb + (long)d * DD;
    const float* __restrict__ w  = WR + r * (DD * DDR) + lane;
    float at = 0.f, ah = 0.f;
#pragma unroll 8
    for (int dd = 0; dd < DD; ++dd) {
        float ws = w[dd * DDR];
        at = fmaf(es[dd], ws, at);
        ah = fmaf(eh[dd], ws, ah);
    }
    float term = at * tanhf(ah + rel[r * DDR + lane]);
#pragma unroll
    for (int off = 32; off; off >>= 1) term += __shfl_xor(term, off);
    if (lane == 0) {
        att[e] = term;
        atomicMax(mkey + d, enc_f(term));
    }
}

__global__ void k_expsum(const int* __restrict__ dst, float* __restrict__ att,
                         const unsigned* __restrict__ mkey, float* __restrict__ ssum)
{
    int e = blockIdx.x * blockDim.x + threadIdx.x;
    if (e >= NE) return;
    int d = dst[e];
    float ex = expf(att[e] - dec_f(mkey[d]));
    att[e] = ex;
    atomicAdd(ssum + d, ex);
}

__global__ void k_agg0(const float* __restrict__ emb, const int* __restrict__ src,
                       const int* __restrict__ dst, float* __restrict__ att,
                       const float* __restrict__ ssum, float* __restrict__ Nh)
{
    int e = (int)((blockIdx.x * blockDim.x + threadIdx.x) >> 6);
    int lane = threadIdx.x & 63;
    if (e >= NE) return;
    int s = src[e], d = dst[e];
    float a = att[e] / ssum[d];
    if (lane == 0) att[e] = a;
    float v = emb[(long)s * DD + lane] * a;
    atomicAdd(Nh + (long)d * DD + lane, v);
}

__global__ void k_agg1(const float* __restrict__ out, const int* __restrict__ src,
                       const int* __restrict__ dst, const float* __restrict__ att,
                       float* __restrict__ Nh1)
{
    int idx = blockIdx.x * blockDim.x + threadIdx.x;
    int e = idx >> 5;
    int j = idx & 31;
    if (e >= NE) return;
    int s = src[e], d = dst[e];
    float a = att[e];
    float v = out[(long)s * 112 + 64 + j] * a;
    atomicAdd(Nh1 + (long)d * 32 + j, v);
}

#define NPB0 32
__global__ void __launch_bounds__(256)
k_node0t(const float* __restrict__ emb, const float* __restrict__ Nh,
         const float* __restrict__ W1, const float* __restrict__ b1,
         const float* __restrict__ W2, const float* __restrict__ b2,
         float* __restrict__ out)
{
    __shared__ float W1T[64][33];
    __shared__ float W2T[64][33];
    int t = threadIdx.x;
#pragma unroll
    for (int i = 0; i < 8; ++i) {
        int idx = i * 256 + t;
        W1T[idx & 63][idx >> 6] = W1[idx];
        W2T[idx & 63][idx >> 6] = W2[idx];
    }
    __syncthreads();
    int wv = t >> 6, lane = t & 63, j = lane & 31;
    const float* __restrict__ WT = (lane < 32) ? &W1T[0][0] : &W2T[0][0];
    float bj = (lane < 32) ? b1[j] : b2[j];
    int n0 = blockIdx.x * NPB0;
    int n1 = (n0 + NPB0 < NN) ? n0 + NPB0 : NN;
    for (int node = n0 + wv; node < n1; node += 4) {
        const float* __restrict__ x  = emb + (long)node * DD;
        const float* __restrict__ nh = Nh + (long)node * DD;
        float acc = 0.f;
#pragma unroll 8
        for (int dd = 0; dd < DD; ++dd) {
            float xv = x[dd], nv = nh[dd];
            float v = (lane < 32) ? (xv + nv) : (xv * nv);
            acc = fmaf(v, WT[dd * 33 + j], acc);
        }
        acc += bj;
        acc = (acc >= 0.f) ? acc : 0.01f * acc;
        float other = __shfl_down(acc, 32);
        float h = acc + other;
        float ss = h * h;
#pragma unroll
        for (int off = 16; off; off >>= 1) ss += __shfl_xor(ss, off);
        float hn = h / fmaxf(sqrtf(ss), 1e-12f);
        out[(long)node * 112 + lane] = x[lane];
        if (lane < 32) out[(long)node * 112 + 64 + j] = hn;
    }
}

#define NPB1 32
__global__ void __launch_bounds__(256)
k_node1t(const float* __restrict__ outbuf, const float* __restrict__ Nh1,
         const float* __restrict__ W1, const float* __restrict__ b1,
         const float* __restrict__ W2, const float* __restrict__ b2,
         float* __restrict__ out)
{
    __shared__ float W1T[32][17];
    __shared__ float W2T[32][17];
    int t = threadIdx.x;
#pragma unroll
    for (int i = 0; i < 2; ++i) {
        int idx = i * 256 + t;
        W1T[idx & 31][idx >> 5] = W1[idx];
        W2T[idx & 31][idx >> 5] = W2[idx];
    }
    __syncthreads();
    int grp = t >> 5;
    int l5 = t & 31, j = l5 & 15;
    const float* __restrict__ WT = (l5 < 16) ? &W1T[0][0] : &W2T[0][0];
    float bj = (l5 < 16) ? b1[j] : b2[j];
    int n0 = blockIdx.x * NPB1;
    int n1 = (n0 + NPB1 < NN) ? n0 + NPB1 : NN;
    for (int node = n0 + grp; node < n1; node += 8) {
        const float* __restrict__ x  = outbuf + (long)node * 112 + 64;
        const float* __restrict__ nh = Nh1 + (long)node * 32;
        float acc = 0.f;
#pragma unroll 8
        for (int dd = 0; dd < 32; ++dd) {
            float xv = x[dd], nv = nh[dd];
            float v = (l5 < 16) ? (xv + nv) : (xv * nv);
            acc = fmaf(v, WT[dd * 17 + j], acc);
        }
        acc += bj;
        acc = (acc >= 0.f) ? acc : 0.01f * acc;
        float other = __shfl_down(acc, 16, 32);
        float h = acc + other;
        float ss = h * h;
#pragma unroll
        for (int off = 8; off; off >>= 1) ss += __shfl_xor(ss, off);
        float hn = h / fmaxf(sqrtf(ss), 1e-12f);
        if (l5 < 16) out[(long)node * 112 + 96 + j] = hn;
    }
}

extern "C" void kernel_launch(void* const* d_in, const int* in_sizes, int n_in,
                              void* d_out, int out_size, void* d_ws, size_t ws_size,
                              hipStream_t stream) {
    const float* emb  = (const float*)d_in[0];
    const float* rel  = (const float*)d_in[1];
    const float* WR   = (const float*)d_in[2];
    const float* W1_0 = (const float*)d_in[3];
    const float* b1_0 = (const float*)d_in[4];
    const float* W2_0 = (const float*)d_in[5];
    const float* b2_0 = (const float*)d_in[6];
    const float* W1_1 = (const float*)d_in[7];
    const float* b1_1 = (const float*)d_in[8];
    const float* W2_1 = (const float*)d_in[9];
    const float* b2_1 = (const float*)d_in[10];
    const int*   src  = (const int*)d_in[11];
    const int*   dst  = (const int*)d_in[12];
    const int*   et   = (const int*)d_in[13];
    float* out = (float*)d_out;

    // main-path workspace (4B units):
    // [cnt NN][gcur 64][base NN][curs NN][acsr NE][srcet NE][tproj][w2h][embh NN*32][h1h NN*16]
    unsigned* cnt   = (unsigned*)d_ws;
    unsigned* gcur  = cnt + NN;
    unsigned* basep = cnt + NN + 64;
    unsigned* curs  = cnt + 2 * NN + 64;
    float* acsr  = (float*)d_ws + 3 * NN + 64;
    unsigned* srcet = (unsigned*)(acsr + NE);
    unsigned short* tproj = (unsigned short*)(srcet + NE);
    unsigned short* w2h = tproj + (size_t)NR * NN * DDR;
    unsigned* embh = (unsigned*)(w2h + (size_t)NR * NN * DDR);
    unsigned short* h1h = (unsigned short*)(embh + (size_t)NN * 32);

    size_t need = ((size_t)3 * NN + 64 + 2 * (size_t)NE) * 4
                + 2 * (size_t)NR * NN * DDR * 2
                + (size_t)NN * 32 * 4 + (size_t)NN * 16 * 4;

    if (ws_size >= need) {
        hipMemsetAsync(d_ws, 0, (size_t)(NN + 64) * sizeof(unsigned), stream);  // cnt + gcur
        k_hist<<<dim3((NE + 255) / 256), dim3(256), 0, stream>>>(dst, cnt);
        k_projm<<<dim3((NN + 127) / 128, NR), dim3(256), 0, stream>>>(
            emb, WR, rel, tproj, embh);
        k_projw2<<<dim3((NN + 127) / 128, NR), dim3(256), 0, stream>>>(
            tproj, WR, (unsigned short*)w2h);
        k_base<<<dim3((NN + 255) / 256), dim3(256), 0, stream>>>(cnt, gcur, basep, curs);
        k_scatter2<<<dim3((NE + 255) / 256), dim3(256), 0, stream>>>(
            dst, src, et, curs, srcet);
        k_mega0<<<dim3((NN + 3) / 4), dim3(256), 0, stream>>>(
            emb, embh, (const unsigned*)w2h, cnt, basep, srcet, acsr, h1h,
            W1_0, b1_0, W2_0, b2_0, out);
        k_mega1<<<dim3((NN + 7) / 8), dim3(256), 0, stream>>>(
            acsr, srcet, cnt, basep, h1h, W1_1, b1_1, W2_1, b2_1, out);
    } else {
        // fallback: atomic pipeline
        unsigned* mkey = (unsigned*)d_ws;
        float* ssum = (float*)d_ws + NN;
        float* fNh0 = (float*)d_ws + 2 * NN;
        float* fNh1 = (float*)d_ws + (2 + DD) * NN;
        float* fatt = (float*)d_ws + (2 + DD + 32) * NN;
        hipMemsetAsync(d_ws, 0, (size_t)(2 + DD + 32) * NN * sizeof(float), stream);
        k_att<<<dim3((int)(((long)NE * 64 + 255) / 256)), dim3(256), 0, stream>>>(
            emb, rel, WR, src, dst, et, fatt, mkey);
        k_expsum<<<dim3((NE + 255) / 256), dim3(256), 0, stream>>>(dst, fatt, mkey, ssum);
        k_agg0<<<dim3((int)(((long)NE * 64 + 255) / 256)), dim3(256), 0, stream>>>(
            emb, src, dst, fatt, ssum, fNh0);
        k_node0t<<<dim3((NN + NPB0 - 1) / NPB0), dim3(256), 0, stream>>>(
            emb, fNh0, W1_0, b1_0, W2_0, b2_0, out);
        k_agg1<<<dim3((int)(((long)NE * 32 + 255) / 256)), dim3(256), 0, stream>>>(
            out, src, dst, fatt, fNh1);
        k_node1t<<<dim3((NN + NPB1 - 1) / NPB1), dim3(256), 0, stream>>>(
            out, fNh1, W1_1, b1_1, W2_1, b2_1, out);
    }
}

// Round 18
// 484.567 us; speedup vs baseline: 1.1233x; 1.1072x over previous
//
#include <hip/hip_runtime.h>
#include <hip/hip_bf16.h>
#include <math.h>

#define NN 100000
#define NE 1600000
#define NR 8
#define DD 64
#define DDR 64

typedef __attribute__((ext_vector_type(8))) short bf8v;   // 8 x bf16 (4 VGPRs)
typedef __attribute__((ext_vector_type(4))) float f4v;    // MFMA accumulator

// ---- helpers ----
__device__ __forceinline__ unsigned enc_f(float f) {
    unsigned u = __float_as_uint(f);
    return (u & 0x80000000u) ? ~u : (u | 0x80000000u);
}
__device__ __forceinline__ float dec_f(unsigned u) {
    return (u & 0x80000000u) ? __uint_as_float(u & 0x7FFFFFFFu) : __uint_as_float(~u);
}
__device__ __forceinline__ float bflo(unsigned u) { return __uint_as_float(u << 16); }
__device__ __forceinline__ float bfhi(unsigned u) { return __uint_as_float(u & 0xFFFF0000u); }
__device__ __forceinline__ float bfs2f(unsigned short u) { return __uint_as_float(((unsigned)u) << 16); }
__device__ __forceinline__ short f2bfs(float x) {
    __hip_bfloat16 h = __float2bfloat16(x);
    return *reinterpret_cast<short*>(&h);
}
__device__ __forceinline__ unsigned pack2bf(short a, short b) {
    return (unsigned)(unsigned short)a | ((unsigned)(unsigned short)b << 16);
}
__device__ __forceinline__ float tanh_fast(float x) {
    x = fminf(fmaxf(x, -15.f), 15.f);
    float e = __expf(2.f * x);
    return (e - 1.f) * __builtin_amdgcn_rcpf(e + 1.f);
}

// ---- Kernel PF: FUSED proj->tanh->w2 (two chained MFMA GEMMs, LDS transpose).
// Phase 1: T = tanh(emb@W_R + rel) -> LDS tile (also emits bf16 embh sidecar).
// Phase 2: w2h = T @ W_R^T via MFMA from LDS. tproj never hits HBM (saves
// ~204MB traffic + a launch vs the separate projm+projw2 pair).
__global__ void __launch_bounds__(256)
k_projf(const float* __restrict__ emb, const float* __restrict__ WR,
        const float* __restrict__ rel,
        unsigned short* __restrict__ w2h, unsigned* __restrict__ embh)
{
    __shared__ unsigned short Tt[128][66];   // +2 pad: breaks 128B-stride bank repeat
    int t = threadIdx.x;
    int wv = t >> 6, l = t & 63;
    int lo = l & 15, hi = l >> 4;
    int r = blockIdx.y;
    int colbase = (wv & 1) * 32;
    int p = wv >> 1;                          // node-half
    int nwbase = blockIdx.x * 128 + p * 64;
    int nlocal = p * 64;

    // ---- phase 1: proj GEMM (B[dd][col] fragments, k=dd) ----
    const float* __restrict__ wb = WR + (long)r * (DD * DDR) + (hi * 8) * DDR + colbase + lo;
    {
        bf8v B00, B01, B10, B11;
#pragma unroll
        for (int j = 0; j < 8; ++j) {
            B00[j] = f2bfs(wb[(0 * 32 + j) * DDR + 0]);
            B01[j] = f2bfs(wb[(1 * 32 + j) * DDR + 0]);
            B10[j] = f2bfs(wb[(0 * 32 + j) * DDR + 16]);
            B11[j] = f2bfs(wb[(1 * 32 + j) * DDR + 16]);
        }
        float rv0 = rel[r * DDR + colbase + lo];
        float rv1 = rel[r * DDR + colbase + lo + 16];

        for (int nt = 0; nt < 4; ++nt) {
            int nb = nwbase + nt * 16;
            int arow = nb + lo;
            float4 xa0 = make_float4(0.f, 0.f, 0.f, 0.f), xa1 = xa0, xb0 = xa0, xb1 = xa0;
            if (arow < NN) {
                const float* __restrict__ xr = emb + (long)arow * DD + hi * 8;
                xa0 = *(const float4*)(xr);
                xa1 = *(const float4*)(xr + 4);
                xb0 = *(const float4*)(xr + 32);
                xb1 = *(const float4*)(xr + 36);
            }
            bf8v A0, A1;
            A0[0] = f2bfs(xa0.x); A0[1] = f2bfs(xa0.y); A0[2] = f2bfs(xa0.z); A0[3] = f2bfs(xa0.w);
            A0[4] = f2bfs(xa1.x); A0[5] = f2bfs(xa1.y); A0[6] = f2bfs(xa1.z); A0[7] = f2bfs(xa1.w);
            A1[0] = f2bfs(xb0.x); A1[1] = f2bfs(xb0.y); A1[2] = f2bfs(xb0.z); A1[3] = f2bfs(xb0.w);
            A1[4] = f2bfs(xb1.x); A1[5] = f2bfs(xb1.y); A1[6] = f2bfs(xb1.z); A1[7] = f2bfs(xb1.w);

            if (r == 0 && arow < NN) {
                unsigned* er = embh + (long)arow * 32 + hi * 4;
                er[0]  = pack2bf(A0[0], A0[1]); er[1]  = pack2bf(A0[2], A0[3]);
                er[2]  = pack2bf(A0[4], A0[5]); er[3]  = pack2bf(A0[6], A0[7]);
                er[16] = pack2bf(A1[0], A1[1]); er[17] = pack2bf(A1[2], A1[3]);
                er[18] = pack2bf(A1[4], A1[5]); er[19] = pack2bf(A1[6], A1[7]);
            }

            f4v acc0 = {0.f, 0.f, 0.f, 0.f}, acc1 = {0.f, 0.f, 0.f, 0.f};
            acc0 = __builtin_amdgcn_mfma_f32_16x16x32_bf16(A0, B00, acc0, 0, 0, 0);
            acc0 = __builtin_amdgcn_mfma_f32_16x16x32_bf16(A1, B01, acc0, 0, 0, 0);
            acc1 = __builtin_amdgcn_mfma_f32_16x16x32_bf16(A0, B10, acc1, 0, 0, 0);
            acc1 = __builtin_amdgcn_mfma_f32_16x16x32_bf16(A1, B11, acc1, 0, 0, 0);

#pragma unroll
            for (int i = 0; i < 4; ++i) {
                int rl = nlocal + nt * 16 + hi * 4 + i;          // local tile row
                Tt[rl][colbase + lo]      = (unsigned short)f2bfs(tanh_fast(acc0[i] + rv0));
                Tt[rl][colbase + lo + 16] = (unsigned short)f2bfs(tanh_fast(acc1[i] + rv1));
            }
        }
    }
    __syncthreads();

    // ---- phase 2: w2 GEMM (B2[k][col=dd] = W_R[r][dd][k]) ----
    const float* __restrict__ wb0 = WR + (long)r * (DD * DDR) + (long)(colbase + lo) * DDR + hi * 8;
    const float* __restrict__ wb1 = wb0 + 16 * DDR;
    bf8v C00, C01, C10, C11;
#pragma unroll
    for (int j = 0; j < 8; ++j) {
        C00[j] = f2bfs(wb0[j]);
        C01[j] = f2bfs(wb0[32 + j]);
        C10[j] = f2bfs(wb1[j]);
        C11[j] = f2bfs(wb1[32 + j]);
    }
    for (int nt = 0; nt < 4; ++nt) {
        int nb = nwbase + nt * 16;
        int rl = nlocal + nt * 16 + lo;
        bf8v A0 = *(const bf8v*)&Tt[rl][hi * 8];
        bf8v A1 = *(const bf8v*)&Tt[rl][32 + hi * 8];
        f4v acc0 = {0.f, 0.f, 0.f, 0.f}, acc1 = {0.f, 0.f, 0.f, 0.f};
        acc0 = __builtin_amdgcn_mfma_f32_16x16x32_bf16(A0, C00, acc0, 0, 0, 0);
        acc0 = __builtin_amdgcn_mfma_f32_16x16x32_bf16(A1, C01, acc0, 0, 0, 0);
        acc1 = __builtin_amdgcn_mfma_f32_16x16x32_bf16(A0, C10, acc1, 0, 0, 0);
        acc1 = __builtin_amdgcn_mfma_f32_16x16x32_bf16(A1, C11, acc1, 0, 0, 0);
#pragma unroll
        for (int i = 0; i < 4; ++i) {
            int rr = nb + hi * 4 + i;
            if (rr < NN) {
                long obase = ((long)r * NN + rr) * DDR + colbase + lo;
                w2h[obase]      = (unsigned short)f2bfs(acc0[i]);
                w2h[obase + 16] = (unsigned short)f2bfs(acc1[i]);
            }
        }
    }
}

// ---- CSR build ----
__global__ void k_hist(const int* __restrict__ dst, unsigned* __restrict__ cnt)
{
    int e = blockIdx.x * blockDim.x + threadIdx.x;
    if (e >= NE) return;
    atomicAdd(cnt + dst[e], 1u);
}

__global__ void k_base(const unsigned* __restrict__ cnt, unsigned* __restrict__ gcur,
                       unsigned* __restrict__ base, unsigned* __restrict__ curs)
{
    int i = blockIdx.x * blockDim.x + threadIdx.x;
    int lane = threadIdx.x & 63;
    unsigned v = (i < NN) ? cnt[i] : 0u;
    unsigned p = v;
#pragma unroll
    for (int off = 1; off < 64; off <<= 1) {
        unsigned q = __shfl_up(p, off);
        if (lane >= off) p += q;
    }
    unsigned tot = __shfl(p, 63);
    unsigned gb = 0;
    if (lane == 0) gb = atomicAdd(gcur, tot);
    gb = __shfl(gb, 0);
    if (i < NN) {
        unsigned b = gb + p - v;
        base[i] = b;
        curs[i] = b;
    }
}

__global__ void k_scatter2(const int* __restrict__ dst, const int* __restrict__ src,
                           const int* __restrict__ et, unsigned* __restrict__ curs,
                           unsigned* __restrict__ srcet)
{
    int e = blockIdx.x * blockDim.x + threadIdx.x;
    if (e >= NE) return;
    unsigned pos = atomicAdd(curs + dst[e], 1u);
    srcet[pos] = (unsigned)src[e] | ((unsigned)et[e] << 28);
}

// ---- MEGA0: att + softmax + agg FUSED per 4-edge chunk. One embh row
// gather per edge total: att dot uses it (16 lanes), then 2 shfls
// redistribute it to all 64 lanes for the aggregation fma. Exact no-max
// softmax (e^a/Σe^a, r15-verified). w2h rows L1-hot per node.
__global__ void __launch_bounds__(256)
k_mega0(const float* __restrict__ emb, const unsigned* __restrict__ embh,
        const unsigned* __restrict__ w2h,
        const unsigned* __restrict__ cnt, const unsigned* __restrict__ basep,
        const unsigned* __restrict__ srcet, float* __restrict__ acsr,
        unsigned short* __restrict__ h1h,
        const float* __restrict__ W1, const float* __restrict__ b1,
        const float* __restrict__ W2, const float* __restrict__ b2,
        float* __restrict__ out)
{
    __shared__ float W1T[64][33];
    __shared__ float W2T[64][33];
    __shared__ float sm1[4][64];
    __shared__ float sm2[4][64];
    int t = threadIdx.x;
#pragma unroll
    for (int i = 0; i < 8; ++i) {
        int idx = i * 256 + t;          // j=idx>>6, dd=idx&63
        W1T[idx & 63][idx >> 6] = W1[idx];
        W2T[idx & 63][idx >> 6] = W2[idx];
    }
    int wv = t >> 6, lane = t & 63;
    int g = blockIdx.x * 4 + wv;        // NN % 4 == 0
    int deg = (int)cnt[g];
    long b = basep[g];
    float Nh = 0.f;
    const unsigned short* embh_us = (const unsigned short*)embh;
    if (deg > 0 && deg <= 64) {
        unsigned se = 0;
        if (lane < deg) se = srcet[b + lane];       // coalesced CSR read
        int gi = lane >> 4;             // edge sub-slot 0..3
        int lj = lane & 15;             // lane within edge group
        float acc = 0.f, s_ = 0.f, myexp = 0.f;
        for (int k0 = 0; k0 < deg; k0 += 4) {
            int ei = k0 + gi;                        // <= 63 always
            unsigned sei = __shfl(se, ei);           // pad-safe (se=0)
            int s = (int)(sei & 0x0FFFFFFFu);
            int r = (int)(sei >> 28);
            uint2 tv = *(const uint2*)(embh + (long)s * 32 + lj * 2);           // L3
            uint2 hv = *(const uint2*)(w2h + ((long)r * NN + g) * 32 + lj * 2); // L1-hot
            float sum = bflo(tv.x) * bflo(hv.x) + bfhi(tv.x) * bfhi(hv.x)
                      + bflo(tv.y) * bflo(hv.y) + bfhi(tv.y) * bfhi(hv.y);
#pragma unroll
            for (int off = 8; off; off >>= 1) sum += __shfl_xor(sum, off);
            // per-edge: broadcast e^att, redistribute the row, accumulate
#pragma unroll
            for (int q = 0; q < 4; ++q) {
                float sq = __shfl(sum, q * 16);
                float exq = (k0 + q < deg) ? __expf(fminf(sq, 60.f)) : 0.f;
                if (lane == k0 + q) myexp = exq;
                s_ += exq;
                int srcl = q * 16 + (lane >> 2);     // holder of element `lane`
                unsigned rx = __shfl(tv.x, srcl);
                unsigned ry = __shfl(tv.y, srcl);
                unsigned word = (lane & 2) ? ry : rx;
                float v = (lane & 1) ? bfhi(word) : bflo(word);
                acc = fmaf(v, exq, acc);
            }
        }
        float inv = 1.f / s_;
        if (lane < deg) acsr[b + lane] = myexp * inv;
        Nh = acc * inv;
    } else if (deg > 64) {
        // slow path (deg>64), full-lane, two-pass max softmax
        float m = -3.4e38f;
        for (int i = 0; i < deg; ++i) {
            unsigned sei = srcet[b + i];
            int s = (int)(sei & 0x0FFFFFFFu), r = (int)(sei >> 28);
            float v = bfs2f(embh_us[(long)s * DD + lane]);
            float wvl = bfs2f(((const unsigned short*)w2h)[((long)r * NN + g) * DDR + lane]);
            float p = v * wvl;
#pragma unroll
            for (int off = 32; off; off >>= 1) p += __shfl_xor(p, off);
            if (lane == 0) acsr[b + i] = p;
            m = fmaxf(m, p);
        }
        float s_ = 0.f;
        for (int i = lane; i < deg; i += 64) s_ += __expf(acsr[b + i] - m);
#pragma unroll
        for (int off = 32; off; off >>= 1) s_ += __shfl_xor(s_, off);
        float inv = 1.f / s_;
        float acc = 0.f;
        for (int i = 0; i < deg; ++i) {
            float raw = acsr[b + i];
            float a = __expf(raw - m) * inv;
            int s = (int)(srcet[b + i] & 0x0FFFFFFFu);
            acc = fmaf(bfs2f(embh_us[(long)s * DD + lane]), a, acc);
            if (lane == 0) acsr[b + i] = a;
        }
        Nh = acc;
    }
    float x = emb[(long)g * DD + lane];
    sm1[wv][lane] = x + Nh;
    sm2[wv][lane] = x * Nh;
    __syncthreads();
    int j = lane & 31;
    const float* __restrict__ WT = (lane < 32) ? &W1T[0][0] : &W2T[0][0];
    const float* __restrict__ sm = (lane < 32) ? &sm1[wv][0] : &sm2[wv][0];
    float accm = (lane < 32) ? b1[j] : b2[j];
#pragma unroll 8
    for (int dd = 0; dd < 64; ++dd)
        accm = fmaf(sm[dd], WT[dd * 33 + j], accm);
    accm = (accm >= 0.f) ? accm : 0.01f * accm;
    float other = __shfl_down(accm, 32);
    float h = accm + other;
    float ss = h * h;
#pragma unroll
    for (int off = 16; off; off >>= 1) ss += __shfl_xor(ss, off);
    float hn = h / fmaxf(sqrtf(ss), 1e-12f);
    out[(long)g * 112 + lane] = x;
    if (lane < 32) {
        out[(long)g * 112 + 64 + j] = hn;
        h1h[(long)g * 32 + j] = (unsigned short)f2bfs(hn);
    }
}

// ---- MEGA1: layer-1 agg (bf16 h1h gathers, 6.4MB) + MLP ----
__global__ void __launch_bounds__(256)
k_mega1(const float* __restrict__ acsr, const unsigned* __restrict__ srcet,
        const unsigned* __restrict__ cnt, const unsigned* __restrict__ basep,
        const unsigned short* __restrict__ h1h,
        const float* __restrict__ W1, const float* __restrict__ b1,
        const float* __restrict__ W2, const float* __restrict__ b2,
        float* __restrict__ out)
{
    __shared__ float W1T[32][17];
    __shared__ float W2T[32][17];
    __shared__ float sm1[8][32];
    __shared__ float sm2[8][32];
    int t = threadIdx.x;
#pragma unroll
    for (int i = 0; i < 2; ++i) {
        int idx = i * 256 + t;
        W1T[idx & 31][idx >> 5] = W1[idx];
        W2T[idx & 31][idx >> 5] = W2[idx];
    }
    int grp = t >> 5, l5 = t & 31;
    int g = blockIdx.x * 8 + grp;       // NN % 8 == 0
    int deg = (int)cnt[g];
    float acc = 0.f;
    if (deg > 0) {
        long b = basep[g];
        unsigned se = 0; float a = 0.f;
        if (l5 < deg) { se = srcet[b + l5]; a = acsr[b + l5]; }
        int dmin = (deg < 32) ? deg : 32;
        int i = 0;
        for (; i + 1 < dmin; i += 2) {
            float a0 = __shfl(a, i, 32), a1 = __shfl(a, i + 1, 32);
            int s0 = (int)(__shfl(se, i, 32) & 0x0FFFFFFFu);
            int s1 = (int)(__shfl(se, i + 1, 32) & 0x0FFFFFFFu);
            float v0 = bfs2f(h1h[(long)s0 * 32 + l5]);
            float v1 = bfs2f(h1h[(long)s1 * 32 + l5]);
            acc = fmaf(v0, a0, acc);
            acc = fmaf(v1, a1, acc);
        }
        if (i < dmin) {
            float a0 = __shfl(a, i, 32);
            int s0 = (int)(__shfl(se, i, 32) & 0x0FFFFFFFu);
            acc = fmaf(bfs2f(h1h[(long)s0 * 32 + l5]), a0, acc);
        }
        for (int k = 32; k < deg; ++k) {
            float ak = acsr[b + k];
            int sk = (int)(srcet[b + k] & 0x0FFFFFFFu);
            acc = fmaf(bfs2f(h1h[(long)sk * 32 + l5]), ak, acc);
        }
    }
    float x = out[(long)g * 112 + 64 + l5];
    sm1[grp][l5] = x + acc;
    sm2[grp][l5] = x * acc;
    __syncthreads();
    int j = l5 & 15;
    const float* __restrict__ WT = (l5 < 16) ? &W1T[0][0] : &W2T[0][0];
    const float* __restrict__ sm = (l5 < 16) ? &sm1[grp][0] : &sm2[grp][0];
    float accm = (l5 < 16) ? b1[j] : b2[j];
#pragma unroll 8
    for (int dd = 0; dd < 32; ++dd)
        accm = fmaf(sm[dd], WT[dd * 17 + j], accm);
    accm = (accm >= 0.f) ? accm : 0.01f * accm;
    float other = __shfl_down(accm, 16, 32);
    float h = accm + other;
    float ss = h * h;
#pragma unroll
    for (int off = 8; off; off >>= 1) ss += __shfl_xor(ss, off);
    float hn = h / fmaxf(sqrtf(ss), 1e-12f);
    if (l5 < 16) out[(long)g * 112 + 96 + j] = hn;
}

// ================= fallback path (ws too small): atomic pipeline =================
__global__ void k_att(const float* __restrict__ emb, const float* __restrict__ rel,
                      const float* __restrict__ WR, const int* __restrict__ src,
                      const int* __restrict__ dst, const int* __restrict__ et,
                      float* __restrict__ att, unsigned* __restrict__ mkey)
{
    int e = (int)((blockIdx.x * blockDim.x + threadIdx.x) >> 6);
    int lane = threadIdx.x & 63;
    if (e >= NE) return;
    int s = src[e], d = dst[e], r = et[e];
    const float* __restrict__ es = emb + (long)s * DD;
    const float* __restrict__ eh = emb + (long)d * DD;
    const float* __restrict__ w  = WR + r * (DD * DDR) + lane;
    float at = 0.f, ah = 0.f;
#pragma unroll 8
    for (int dd = 0; dd < DD; ++dd) {
        float ws = w[dd * DDR];
        at = fmaf(es[dd], ws, at);
        ah = fmaf(eh[dd], ws, ah);
    }
    float term = at * tanhf(ah + rel[r * DDR + lane]);
#pragma unroll
    for (int off = 32; off; off >>= 1) term += __shfl_xor(term, off);
    if (lane == 0) {
        att[e] = term;
        atomicMax(mkey + d, enc_f(term));
    }
}

__global__ void k_expsum(const int* __restrict__ dst, float* __restrict__ att,
                         const unsigned* __restrict__ mkey, float* __restrict__ ssum)
{
    int e = blockIdx.x * blockDim.x + threadIdx.x;
    if (e >= NE) return;
    int d = dst[e];
    float ex = expf(att[e] - dec_f(mkey[d]));
    att[e] = ex;
    atomicAdd(ssum + d, ex);
}

__global__ void k_agg0(const float* __restrict__ emb, const int* __restrict__ src,
                       const int* __restrict__ dst, float* __restrict__ att,
                       const float* __restrict__ ssum, float* __restrict__ Nh)
{
    int e = (int)((blockIdx.x * blockDim.x + threadIdx.x) >> 6);
    int lane = threadIdx.x & 63;
    if (e >= NE) return;
    int s = src[e], d = dst[e];
    float a = att[e] / ssum[d];
    if (lane == 0) att[e] = a;
    float v = emb[(long)s * DD + lane] * a;
    atomicAdd(Nh + (long)d * DD + lane, v);
}

__global__ void k_agg1(const float* __restrict__ out, const int* __restrict__ src,
                       const int* __restrict__ dst, const float* __restrict__ att,
                       float* __restrict__ Nh1)
{
    int idx = blockIdx.x * blockDim.x + threadIdx.x;
    int e = idx >> 5;
    int j = idx & 31;
    if (e >= NE) return;
    int s = src[e], d = dst[e];
    float a = att[e];
    float v = out[(long)s * 112 + 64 + j] * a;
    atomicAdd(Nh1 + (long)d * 32 + j, v);
}

#define NPB0 32
__global__ void __launch_bounds__(256)
k_node0t(const float* __restrict__ emb, const float* __restrict__ Nh,
         const float* __restrict__ W1, const float* __restrict__ b1,
         const float* __restrict__ W2, const float* __restrict__ b2,
         float* __restrict__ out)
{
    __shared__ float W1T[64][33];
    __shared__ float W2T[64][33];
    int t = threadIdx.x;
#pragma unroll
    for (int i = 0; i < 8; ++i) {
        int idx = i * 256 + t;
        W1T[idx & 63][idx >> 6] = W1[idx];
        W2T[idx & 63][idx >> 6] = W2[idx];
    }
    __syncthreads();
    int wv = t >> 6, lane = t & 63, j = lane & 31;
    const float* __restrict__ WT = (lane < 32) ? &W1T[0][0] : &W2T[0][0];
    float bj = (lane < 32) ? b1[j] : b2[j];
    int n0 = blockIdx.x * NPB0;
    int n1 = (n0 + NPB0 < NN) ? n0 + NPB0 : NN;
    for (int node = n0 + wv; node < n1; node += 4) {
        const float* __restrict__ x  = emb + (long)node * DD;
        const float* __restrict__ nh = Nh + (long)node * DD;
        float acc = 0.f;
#pragma unroll 8
        for (int dd = 0; dd < DD; ++dd) {
            float xv = x[dd], nv = nh[dd];
            float v = (lane < 32) ? (xv + nv) : (xv * nv);
            acc = fmaf(v, WT[dd * 33 + j], acc);
        }
        acc += bj;
        acc = (acc >= 0.f) ? acc : 0.01f * acc;
        float other = __shfl_down(acc, 32);
        float h = acc + other;
        float ss = h * h;
#pragma unroll
        for (int off = 16; off; off >>= 1) ss += __shfl_xor(ss, off);
        float hn = h / fmaxf(sqrtf(ss), 1e-12f);
        out[(long)node * 112 + lane] = x[lane];
        if (lane < 32) out[(long)node * 112 + 64 + j] = hn;
    }
}

#define NPB1 32
__global__ void __launch_bounds__(256)
k_node1t(const float* __restrict__ outbuf, const float* __restrict__ Nh1,
         const float* __restrict__ W1, const float* __restrict__ b1,
         const float* __restrict__ W2, const float* __restrict__ b2,
         float* __restrict__ out)
{
    __shared__ float W1T[32][17];
    __shared__ float W2T[32][17];
    int t = threadIdx.x;
#pragma unroll
    for (int i = 0; i < 2; ++i) {
        int idx = i * 256 + t;
        W1T[idx & 31][idx >> 5] = W1[idx];
        W2T[idx & 31][idx >> 5] = W2[idx];
    }
    __syncthreads();
    int grp = t >> 5;
    int l5 = t & 31, j = l5 & 15;
    const float* __restrict__ WT = (l5 < 16) ? &W1T[0][0] : &W2T[0][0];
    float bj = (l5 < 16) ? b1[j] : b2[j];
    int n0 = blockIdx.x * NPB1;
    int n1 = (n0 + NPB1 < NN) ? n0 + NPB1 : NN;
    for (int node = n0 + grp; node < n1; node += 8) {
        const float* __restrict__ x  = outbuf + (long)node * 112 + 64;
        const float* __restrict__ nh = Nh1 + (long)node * 32;
        float acc = 0.f;
#pragma unroll 8
        for (int dd = 0; dd < 32; ++dd) {
            float xv = x[dd], nv = nh[dd];
            float v = (l5 < 16) ? (xv + nv) : (xv * nv);
            acc = fmaf(v, WT[dd * 17 + j], acc);
        }
        acc += bj;
        acc = (acc >= 0.f) ? acc : 0.01f * acc;
        float other = __shfl_down(acc, 16, 32);
        float h = acc + other;
        float ss = h * h;
#pragma unroll
        for (int off = 8; off; off >>= 1) ss += __shfl_xor(ss, off);
        float hn = h / fmaxf(sqrtf(ss), 1e-12f);
        if (l5 < 16) out[(long)node * 112 + 96 + j] = hn;
    }
}

extern "C" void kernel_launch(void* const* d_in, const int* in_sizes, int n_in,
                              void* d_out, int out_size, void* d_ws, size_t ws_size,
                              hipStream_t stream) {
    const float* emb  = (const float*)d_in[0];
    const float* rel  = (const float*)d_in[1];
    const float* WR   = (const float*)d_in[2];
    const float* W1_0 = (const float*)d_in[3];
    const float* b1_0 = (const float*)d_in[4];
    const float* W2_0 = (const float*)d_in[5];
    const float* b2_0 = (const float*)d_in[6];
    const float* W1_1 = (const float*)d_in[7];
    const float* b1_1 = (const float*)d_in[8];
    const float* W2_1 = (const float*)d_in[9];
    const float* b2_1 = (const float*)d_in[10];
    const int*   src  = (const int*)d_in[11];
    const int*   dst  = (const int*)d_in[12];
    const int*   et   = (const int*)d_in[13];
    float* out = (float*)d_out;

    // main-path workspace (4B units):
    // [cnt NN][gcur 64][base NN][curs NN][acsr NE][srcet NE][w2h][embh NN*32][h1h NN*16]
    unsigned* cnt   = (unsigned*)d_ws;
    unsigned* gcur  = cnt + NN;
    unsigned* basep = cnt + NN + 64;
    unsigned* curs  = cnt + 2 * NN + 64;
    float* acsr  = (float*)d_ws + 3 * NN + 64;
    unsigned* srcet = (unsigned*)(acsr + NE);
    unsigned short* w2h = (unsigned short*)(srcet + NE);
    unsigned* embh = (unsigned*)(w2h + (size_t)NR * NN * DDR);
    unsigned short* h1h = (unsigned short*)(embh + (size_t)NN * 32);

    size_t need = ((size_t)3 * NN + 64 + 2 * (size_t)NE) * 4
                + (size_t)NR * NN * DDR * 2
                + (size_t)NN * 32 * 4 + (size_t)NN * 16 * 4;

    if (ws_size >= need) {
        hipMemsetAsync(d_ws, 0, (size_t)(NN + 64) * sizeof(unsigned), stream);  // cnt + gcur
        k_hist<<<dim3((NE + 255) / 256), dim3(256), 0, stream>>>(dst, cnt);
        k_projf<<<dim3((NN + 127) / 128, NR), dim3(256), 0, stream>>>(
            emb, WR, rel, w2h, embh);
        k_base<<<dim3((NN + 255) / 256), dim3(256), 0, stream>>>(cnt, gcur, basep, curs);
        k_scatter2<<<dim3((NE + 255) / 256), dim3(256), 0, stream>>>(
            dst, src, et, curs, srcet);
        k_mega0<<<dim3((NN + 3) / 4), dim3(256), 0, stream>>>(
            emb, embh, (const unsigned*)w2h, cnt, basep, srcet, acsr, h1h,
            W1_0, b1_0, W2_0, b2_0, out);
        k_mega1<<<dim3((NN + 7) / 8), dim3(256), 0, stream>>>(
            acsr, srcet, cnt, basep, h1h, W1_1, b1_1, W2_1, b2_1, out);
    } else {
        // fallback: atomic pipeline
        unsigned* mkey = (unsigned*)d_ws;
        float* ssum = (float*)d_ws + NN;
        float* fNh0 = (float*)d_ws + 2 * NN;
        float* fNh1 = (float*)d_ws + (2 + DD) * NN;
        float* fatt = (float*)d_ws + (2 + DD + 32) * NN;
        hipMemsetAsync(d_ws, 0, (size_t)(2 + DD + 32) * NN * sizeof(float), stream);
        k_att<<<dim3((int)(((long)NE * 64 + 255) / 256)), dim3(256), 0, stream>>>(
            emb, rel, WR, src, dst, et, fatt, mkey);
        k_expsum<<<dim3((NE + 255) / 256), dim3(256), 0, stream>>>(dst, fatt, mkey, ssum);
        k_agg0<<<dim3((int)(((long)NE * 64 + 255) / 256)), dim3(256), 0, stream>>>(
            emb, src, dst, fatt, ssum, fNh0);
        k_node0t<<<dim3((NN + NPB0 - 1) / NPB0), dim3(256), 0, stream>>>(
            emb, fNh0, W1_0, b1_0, W2_0, b2_0, out);
        k_agg1<<<dim3((int)(((long)NE * 32 + 255) / 256)), dim3(256), 0, stream>>>(
            out, src, dst, fatt, fNh1);
        k_node1t<<<dim3((NN + NPB1 - 1) / NPB1), dim3(256), 0, stream>>>(
            out, fNh1, W1_1, b1_1, W2_1, b2_1, out);
    }
}